// Round 4
// baseline (217.215 us; speedup 1.0000x reference)
//
#include <hip/hip_runtime.h>
#include <math.h>

#define NB 32
#define NT 512
#define NS 64
#define NOBS 4
#define NEMB 32
#define NPE 16
#define NATTN 10
#define ND 26  // ATTN + PE

typedef _Float16 half8_t __attribute__((ext_vector_type(8)));

// obs_emb_weights LDS layout: 64 rows (sensor s) x 128 dwords (o*32+e),
// 16B-chunk XOR swizzle so per-lane ds_read_b128 of row s spreads banks.
__device__ __forceinline__ int obs_idx(int s, int chunk) {
    return (s << 7) + (((chunk ^ (s & 7)) & 31) << 2);
}

__device__ __forceinline__ float2 unpack_h2(unsigned u) {
    unsigned short l16 = (unsigned short)(u & 0xffffu);
    unsigned short h16 = (unsigned short)(u >> 16);
    _Float16 lo, hi;
    __builtin_memcpy(&lo, &l16, 2);
    __builtin_memcpy(&hi, &h16, 2);
    return make_float2((float)lo, (float)hi);
}

// ---------------------------------------------------------------------------
// Kernel A (compute-bound): per (b,t,s) row compute hq[0..9] and beta
// (= recv_b + PE-part dot), store 16 f16 (32B) per row into workspace.
// ---------------------------------------------------------------------------
__global__ __launch_bounds__(512)
void hq_kernel(const float* __restrict__ x,
               const float* __restrict__ times,
               const float* __restrict__ mask,
               const float* __restrict__ obsW,
               const float* __restrict__ recvW,
               const float* __restrict__ recvB,
               half8_t* __restrict__ hqbuf)
{
    __shared__ float lds[NS * 128];  // 32 KiB swizzled obsW tile

    const int tid = threadIdx.x;
#pragma unroll
    for (int k = 0; k < 4; ++k) {
        int i = (tid << 2) + (k << 11);
        float4 v = *reinterpret_cast<const float4*>(obsW + i);
        *reinterpret_cast<float4*>(&lds[obs_idx(i >> 7, (i & 127) >> 2)]) = v;
    }

    const int lane = tid & 63;
    const int wv = tid >> 6;
    const int bt = blockIdx.x * 8 + wv;   // one wave per (b,t)
    const int s = lane;

    // positional encoding (wave-uniform; div[i] = 10^(-i/2))
    const float tt = times[bt];
    const float divs[8] = {1.0f, 0.31622776601683794f, 0.1f, 0.031622776601683794f,
                           0.01f, 0.0031622776601683794f, 0.001f, 0.00031622776601683794f};
    float pe[NPE];
#pragma unroll
    for (int i = 0; i < 8; ++i) {
        float ang = tt * divs[i];
        pe[2 * i]     = __sinf(ang);
        pe[2 * i + 1] = __cosf(ang);
    }

    const float4 xv = *reinterpret_cast<const float4*>(x + ((size_t)bt * NS + s) * NOBS);
    const float  mv = mask[(size_t)bt * NS + s];

    __syncthreads();  // obsW tile ready (the ONLY barrier)

    float hq[ND];
#pragma unroll
    for (int d = 0; d < ND; ++d) hq[d] = recvB[d];  // uniform -> s_load

#pragma unroll
    for (int eb = 0; eb < 8; ++eb) {
        float a0 = 0.f, a1 = 0.f, a2 = 0.f, a3 = 0.f;
        {
            float4 w0 = *reinterpret_cast<const float4*>(&lds[obs_idx(s, 0 * 8 + eb)]);
            a0 += xv.x * w0.x; a1 += xv.x * w0.y; a2 += xv.x * w0.z; a3 += xv.x * w0.w;
            float4 w1 = *reinterpret_cast<const float4*>(&lds[obs_idx(s, 1 * 8 + eb)]);
            a0 += xv.y * w1.x; a1 += xv.y * w1.y; a2 += xv.y * w1.z; a3 += xv.y * w1.w;
            float4 w2 = *reinterpret_cast<const float4*>(&lds[obs_idx(s, 2 * 8 + eb)]);
            a0 += xv.z * w2.x; a1 += xv.z * w2.y; a2 += xv.z * w2.z; a3 += xv.z * w2.w;
            float4 w3 = *reinterpret_cast<const float4*>(&lds[obs_idx(s, 3 * 8 + eb)]);
            a0 += xv.w * w3.x; a1 += xv.w * w3.y; a2 += xv.w * w3.z; a3 += xv.w * w3.w;
        }
        const float h0 = fmaxf(a0, 0.f) * mv;
        const float h1 = fmaxf(a1, 0.f) * mv;
        const float h2 = fmaxf(a2, 0.f) * mv;
        const float h3 = fmaxf(a3, 0.f) * mv;
        const float* rw = recvW + (eb * 4) * ND;  // uniform base -> s_load
#pragma unroll
        for (int d = 0; d < ND; ++d) {
            hq[d] += h0 * rw[d] + h1 * rw[ND + d] + h2 * rw[2 * ND + d] + h3 * rw[3 * ND + d];
        }
    }

    float beta = 0.f;
#pragma unroll
    for (int p = 0; p < NPE; ++p) beta += hq[NATTN + p] * pe[p];

    // pack row: h[0..7]=hq0..7 | h[8]=hq8 h[9]=hq9 h[10]=beta h[11..15]=0
    half8_t lo, hi;
#pragma unroll
    for (int q = 0; q < 8; ++q) lo[q] = (_Float16)hq[q];
    hi[0] = (_Float16)hq[8];
    hi[1] = (_Float16)hq[9];
    hi[2] = (_Float16)beta;
    hi[3] = hi[4] = hi[5] = hi[6] = hi[7] = (_Float16)0.0f;

    half8_t* rp = hqbuf + (((size_t)bt * NS + s) << 1);
    rp[0] = lo;
    rp[1] = hi;
}

// ---------------------------------------------------------------------------
// Kernel B (store-bound): alpha[row][u] = relu(beta_row + hq_row . attnW[u]).
// lane = u (attnW row in 10 VGPRs); wave walks 128 contiguous rows; row data
// via wave-uniform s_load (scalar pipe); one coalesced 256B store per row.
// No LDS, no barriers.
// ---------------------------------------------------------------------------
__global__ __launch_bounds__(256)
void alpha_kernel(const uint4* __restrict__ hqbuf,
                  const float* __restrict__ attnW,
                  float* __restrict__ out)
{
    const int lane = threadIdx.x & 63;
    const int wid = __builtin_amdgcn_readfirstlane((int)(blockIdx.x << 2) + (int)(threadIdx.x >> 6));

    float aW[NATTN];
    {
        const float2* ap = reinterpret_cast<const float2*>(attnW + lane * NATTN);
        float2 a0 = ap[0], a1 = ap[1], a2 = ap[2], a3 = ap[3], a4 = ap[4];
        aW[0] = a0.x; aW[1] = a0.y; aW[2] = a1.x; aW[3] = a1.y; aW[4] = a2.x;
        aW[5] = a2.y; aW[6] = a3.x; aW[7] = a3.y; aW[8] = a4.x; aW[9] = a4.y;
    }

    const size_t r0 = (size_t)wid * 128;          // 128 rows per wave
    const uint4* hp = hqbuf + (r0 << 1);          // 2 x 16B per row
    float* op = out + (r0 << 6) + lane;

#pragma unroll 4
    for (int r = 0; r < 128; ++r) {
        uint4 a = hp[2 * r];                      // uniform addr -> s_load_dwordx4
        uint4 b = hp[2 * r + 1];
        float2 q01 = unpack_h2(a.x), q23 = unpack_h2(a.y);
        float2 q45 = unpack_h2(a.z), q67 = unpack_h2(a.w);
        float2 q89 = unpack_h2(b.x), qb  = unpack_h2(b.y);
        float acc = qb.x;                         // beta
        acc += q01.x * aW[0]; acc += q01.y * aW[1];
        acc += q23.x * aW[2]; acc += q23.y * aW[3];
        acc += q45.x * aW[4]; acc += q45.y * aW[5];
        acc += q67.x * aW[6]; acc += q67.y * aW[7];
        acc += q89.x * aW[8]; acc += q89.y * aW[9];
        op[(size_t)r << 6] = fmaxf(acc, 0.f);     // 64 lanes x 4B contiguous
    }
}

// ---------------------------------------------------------------------------
// Fallback (proven 80us fused R2 kernel) if ws_size is too small.
// ---------------------------------------------------------------------------
__global__ __launch_bounds__(512)
void fused_kernel(const float* __restrict__ x,
                  const float* __restrict__ times,
                  const float* __restrict__ mask,
                  const float* __restrict__ obsW,
                  const float* __restrict__ attnW,
                  const float* __restrict__ recvW,
                  const float* __restrict__ recvB,
                  float* __restrict__ out)
{
    __shared__ float lds[NS * 128];

    const int tid = threadIdx.x;
#pragma unroll
    for (int k = 0; k < 4; ++k) {
        int i = (tid << 2) + (k << 11);
        float4 v = *reinterpret_cast<const float4*>(obsW + i);
        *reinterpret_cast<float4*>(&lds[obs_idx(i >> 7, (i & 127) >> 2)]) = v;
    }

    const int lane = tid & 63;
    const int wv = tid >> 6;
    const int bt = blockIdx.x * 8 + wv;
    const int s = lane;

    float aW[NATTN];
    {
        const float2* ap = reinterpret_cast<const float2*>(attnW + lane * NATTN);
        float2 a0 = ap[0], a1 = ap[1], a2 = ap[2], a3 = ap[3], a4 = ap[4];
        aW[0] = a0.x; aW[1] = a0.y; aW[2] = a1.x; aW[3] = a1.y; aW[4] = a2.x;
        aW[5] = a2.y; aW[6] = a3.x; aW[7] = a3.y; aW[8] = a4.x; aW[9] = a4.y;
    }

    const float tt = times[bt];
    const float divs[8] = {1.0f, 0.31622776601683794f, 0.1f, 0.031622776601683794f,
                           0.01f, 0.0031622776601683794f, 0.001f, 0.00031622776601683794f};
    float pe[NPE];
#pragma unroll
    for (int i = 0; i < 8; ++i) {
        float ang = tt * divs[i];
        pe[2 * i]     = __sinf(ang);
        pe[2 * i + 1] = __cosf(ang);
    }

    const float4 xv = *reinterpret_cast<const float4*>(x + ((size_t)bt * NS + s) * NOBS);
    const float  mv = mask[(size_t)bt * NS + s];

    __syncthreads();

    float hq[ND];
#pragma unroll
    for (int d = 0; d < ND; ++d) hq[d] = recvB[d];

#pragma unroll
    for (int eb = 0; eb < 8; ++eb) {
        float a0 = 0.f, a1 = 0.f, a2 = 0.f, a3 = 0.f;
        {
            float4 w0 = *reinterpret_cast<const float4*>(&lds[obs_idx(s, 0 * 8 + eb)]);
            a0 += xv.x * w0.x; a1 += xv.x * w0.y; a2 += xv.x * w0.z; a3 += xv.x * w0.w;
            float4 w1 = *reinterpret_cast<const float4*>(&lds[obs_idx(s, 1 * 8 + eb)]);
            a0 += xv.y * w1.x; a1 += xv.y * w1.y; a2 += xv.y * w1.z; a3 += xv.y * w1.w;
            float4 w2 = *reinterpret_cast<const float4*>(&lds[obs_idx(s, 2 * 8 + eb)]);
            a0 += xv.z * w2.x; a1 += xv.z * w2.y; a2 += xv.z * w2.z; a3 += xv.z * w2.w;
            float4 w3 = *reinterpret_cast<const float4*>(&lds[obs_idx(s, 3 * 8 + eb)]);
            a0 += xv.w * w3.x; a1 += xv.w * w3.y; a2 += xv.w * w3.z; a3 += xv.w * w3.w;
        }
        const float h0 = fmaxf(a0, 0.f) * mv;
        const float h1 = fmaxf(a1, 0.f) * mv;
        const float h2 = fmaxf(a2, 0.f) * mv;
        const float h3 = fmaxf(a3, 0.f) * mv;
        const float* rw = recvW + (eb * 4) * ND;
#pragma unroll
        for (int d = 0; d < ND; ++d) {
            hq[d] += h0 * rw[d] + h1 * rw[ND + d] + h2 * rw[2 * ND + d] + h3 * rw[3 * ND + d];
        }
    }

    float beta = 0.f;
#pragma unroll
    for (int p = 0; p < NPE; ++p) beta += hq[NATTN + p] * pe[p];

    __syncthreads();

    float* hbase = &lds[wv * (NS * 12)];
    {
        float* hrow = hbase + s * 12;
        float4 v0 = {hq[0], hq[1], hq[2], hq[3]};
        float4 v1 = {hq[4], hq[5], hq[6], hq[7]};
        float4 v2 = {hq[8], hq[9], beta, 0.f};
        *reinterpret_cast<float4*>(hrow)     = v0;
        *reinterpret_cast<float4*>(hrow + 4) = v1;
        *reinterpret_cast<float4*>(hrow + 8) = v2;
    }

    float* obase = out + (size_t)bt * (NS * NS) + lane;
#pragma unroll 4
    for (int r = 0; r < NS; ++r) {
        const float* hr = hbase + r * 12;
        float4 h0 = *reinterpret_cast<const float4*>(hr);
        float4 h1 = *reinterpret_cast<const float4*>(hr + 4);
        float4 h2 = *reinterpret_cast<const float4*>(hr + 8);
        float acc = h2.z;
        acc += h0.x * aW[0]; acc += h0.y * aW[1];
        acc += h0.z * aW[2]; acc += h0.w * aW[3];
        acc += h1.x * aW[4]; acc += h1.y * aW[5];
        acc += h1.z * aW[6]; acc += h1.w * aW[7];
        acc += h2.x * aW[8]; acc += h2.y * aW[9];
        obase[r * NS] = fmaxf(acc, 0.f);
    }
}

extern "C" void kernel_launch(void* const* d_in, const int* in_sizes, int n_in,
                              void* d_out, int out_size, void* d_ws, size_t ws_size,
                              hipStream_t stream) {
    const float* x     = (const float*)d_in[0];
    const float* times = (const float*)d_in[1];
    const float* mask  = (const float*)d_in[2];
    const float* obsW  = (const float*)d_in[3];
    const float* attnW = (const float*)d_in[4];
    const float* recvW = (const float*)d_in[5];
    const float* recvB = (const float*)d_in[6];
    float* out = (float*)d_out;

    const size_t need = (size_t)NB * NT * NS * 16 * sizeof(_Float16);  // 32 MiB
    if (ws_size >= need) {
        half8_t* hqbuf = (half8_t*)d_ws;
        hq_kernel<<<dim3((NB * NT) / 8), dim3(512), 0, stream>>>(
            x, times, mask, obsW, recvW, recvB, hqbuf);
        // 1,048,576 rows / (128 rows/wave * 4 waves/block) = 2048 blocks
        alpha_kernel<<<dim3(2048), dim3(256), 0, stream>>>(
            (const uint4*)d_ws, attnW, out);
    } else {
        fused_kernel<<<dim3((NB * NT) / 8), dim3(512), 0, stream>>>(
            x, times, mask, obsW, attnW, recvW, recvB, out);
    }
}

// Round 5
// 70.963 us; speedup vs baseline: 3.0609x; 3.0609x over previous
//
#include <hip/hip_runtime.h>
#include <math.h>

#define NB 32
#define NT 512
#define NS 64
#define NOBS 4
#define NEMB 32
#define NPE 16
#define NATTN 10
#define ND 26  // ATTN + PE

// obs_emb_weights LDS layout: 64 rows (sensor s) x 128 dwords (o*32+e),
// 16B-chunk XOR swizzle so per-lane ds_read_b128 of row s spreads banks.
__device__ __forceinline__ int obs_idx(int s, int chunk) {
    return (s << 7) + (((chunk ^ (s & 7)) & 31) << 2);
}

__global__ __launch_bounds__(512)
void raindrop_kernel(const float* __restrict__ x,
                     const float* __restrict__ times,
                     const float* __restrict__ mask,
                     const float* __restrict__ obsW,
                     const float* __restrict__ attnW,
                     const float* __restrict__ recvW,
                     const float* __restrict__ recvB,
                     float* __restrict__ out)
{
    // 32 KiB, reused: phase 1 = swizzled obsW tile; phase 3 = hq rows
    __shared__ float lds[NS * 128];
    // per-wave folded PE weights: w_pe[e] = sum_p recvW[e][10+p]*pe[p]
    __shared__ float wpe[8 * NEMB];  // 1 KiB

    const int tid = threadIdx.x;

    // Stage S*OBS*EMB = 8192 floats into LDS (coalesced global float4 reads,
    // swizzled LDS writes). 512 threads x 4 iters x 4 floats.
#pragma unroll
    for (int k = 0; k < 4; ++k) {
        int i = (tid << 2) + (k << 11);
        float4 v = *reinterpret_cast<const float4*>(obsW + i);
        *reinterpret_cast<float4*>(&lds[obs_idx(i >> 7, (i & 127) >> 2)]) = v;
    }

    const int lane = tid & 63;
    const int wv = tid >> 6;
    const int bt = blockIdx.x * 8 + wv;   // one wave per (b,t)
    const int s = lane;                   // phase-1 role: lane = sensor

    // per-lane attnW row for phase-3 role u = lane (10 VGPRs, loaded once)
    float aW[NATTN];
    {
        const float2* ap = reinterpret_cast<const float2*>(attnW + lane * NATTN);
        float2 a0 = ap[0], a1 = ap[1], a2 = ap[2], a3 = ap[3], a4 = ap[4];
        aW[0] = a0.x; aW[1] = a0.y; aW[2] = a1.x; aW[3] = a1.y; aW[4] = a2.x;
        aW[5] = a2.y; aW[6] = a3.x; aW[7] = a3.y; aW[8] = a4.x; aW[9] = a4.y;
    }

    // positional encoding (wave-uniform; div[i] = 10^(-i/2)); native sin/cos
    const float tt = times[bt];
    const float divs[8] = {1.0f, 0.31622776601683794f, 0.1f, 0.031622776601683794f,
                           0.01f, 0.0031622776601683794f, 0.001f, 0.00031622776601683794f};
    float pe[NPE];
#pragma unroll
    for (int i = 0; i < 8; ++i) {
        float ang = tt * divs[i];
        pe[2 * i]     = __sinf(ang);
        pe[2 * i + 1] = __cosf(ang);
    }

    // c0 = recvB[10:26] . pe  (uniform; recvB via s_load)
    float c0 = 0.f;
#pragma unroll
    for (int p = 0; p < NPE; ++p) c0 += recvB[NATTN + p] * pe[p];

    // w_pe: lane e (= lane&31) folds recvW[e][10..25] with pe -> LDS strip.
    // recvW row stride 26 floats; +10 offset is 8B-aligned -> float2 loads.
    {
        const int e = lane & 31;
        const float2* rp = reinterpret_cast<const float2*>(recvW + e * ND + NATTN);
        float acc = 0.f;
#pragma unroll
        for (int p2 = 0; p2 < 8; ++p2) {
            float2 w = rp[p2];
            acc += w.x * pe[2 * p2];
            acc += w.y * pe[2 * p2 + 1];
        }
        if (lane < NEMB) wpe[wv * NEMB + e] = acc;
    }

    // per-lane inputs (coalesced: 64 lanes x 16B contiguous)
    const float4 xv = *reinterpret_cast<const float4*>(x + ((size_t)bt * NS + s) * NOBS);
    const float  mv = mask[(size_t)bt * NS + s];

    __syncthreads();  // obsW tile ready (w_pe write also ordered before this)

    // hq[a] = recv_b[a] + sum_e h_e * recv_W[e][a]   (a = 0..9 only)
    // beta' = sum_e h_e * w_pe[e]
    float hq[NATTN];
#pragma unroll
    for (int a = 0; a < NATTN; ++a) hq[a] = recvB[a];  // uniform -> s_load
    float betah = 0.f;

    const float* wpb = &wpe[wv * NEMB];

#pragma unroll
    for (int eb = 0; eb < 8; ++eb) {  // e = eb*4 + j
        float a0 = 0.f, a1 = 0.f, a2 = 0.f, a3 = 0.f;
        {
            float4 w0 = *reinterpret_cast<const float4*>(&lds[obs_idx(s, 0 * 8 + eb)]);
            a0 += xv.x * w0.x; a1 += xv.x * w0.y; a2 += xv.x * w0.z; a3 += xv.x * w0.w;
            float4 w1 = *reinterpret_cast<const float4*>(&lds[obs_idx(s, 1 * 8 + eb)]);
            a0 += xv.y * w1.x; a1 += xv.y * w1.y; a2 += xv.y * w1.z; a3 += xv.y * w1.w;
            float4 w2 = *reinterpret_cast<const float4*>(&lds[obs_idx(s, 2 * 8 + eb)]);
            a0 += xv.z * w2.x; a1 += xv.z * w2.y; a2 += xv.z * w2.z; a3 += xv.z * w2.w;
            float4 w3 = *reinterpret_cast<const float4*>(&lds[obs_idx(s, 3 * 8 + eb)]);
            a0 += xv.w * w3.x; a1 += xv.w * w3.y; a2 += xv.w * w3.z; a3 += xv.w * w3.w;
        }
        const float h0 = fmaxf(a0, 0.f) * mv;
        const float h1 = fmaxf(a1, 0.f) * mv;
        const float h2 = fmaxf(a2, 0.f) * mv;
        const float h3 = fmaxf(a3, 0.f) * mv;

        // beta' contribution: uniform ds_read_b128 broadcast of 4 w_pe values
        float4 wp = *reinterpret_cast<const float4*>(wpb + eb * 4);
        betah += h0 * wp.x + h1 * wp.y + h2 * wp.z + h3 * wp.w;

        const float* rw = recvW + (eb * 4) * ND;  // uniform base -> s_load
#pragma unroll
        for (int a = 0; a < NATTN; ++a) {
            hq[a] += h0 * rw[a] + h1 * rw[ND + a] + h2 * rw[2 * ND + a] + h3 * rw[3 * ND + a];
        }
    }

    const float beta = c0 + betah;

    __syncthreads();  // all waves done READING the obsW tile -> safe to reuse

    // Stage this wave's hq rows (wave-private region, 64 rows x 12 floats).
    float* hbase = &lds[wv * (NS * 12)];
    {
        float* hrow = hbase + s * 12;
        float4 v0 = {hq[0], hq[1], hq[2], hq[3]};
        float4 v1 = {hq[4], hq[5], hq[6], hq[7]};
        float4 v2 = {hq[8], hq[9], beta, 0.f};
        *reinterpret_cast<float4*>(hrow)     = v0;
        *reinterpret_cast<float4*>(hrow + 4) = v1;
        *reinterpret_cast<float4*>(hrow + 8) = v2;
    }
    // No barrier: this wave reads only rows written by its own lanes, and
    // DS ops from one wave complete in program order.

    // Phase 3: lane = u. For each sensor row r: broadcast its hq (uniform
    // ds_read_b128 x3), 10 FMAs vs per-lane aW, one fully-coalesced 256B store.
    float* obase = out + (size_t)bt * (NS * NS) + lane;
#pragma unroll 4
    for (int r = 0; r < NS; ++r) {
        const float* hr = hbase + r * 12;
        float4 h0 = *reinterpret_cast<const float4*>(hr);
        float4 h1 = *reinterpret_cast<const float4*>(hr + 4);
        float4 h2 = *reinterpret_cast<const float4*>(hr + 8);
        float acc = h2.z;  // beta_r
        acc += h0.x * aW[0]; acc += h0.y * aW[1];
        acc += h0.z * aW[2]; acc += h0.w * aW[3];
        acc += h1.x * aW[4]; acc += h1.y * aW[5];
        acc += h1.z * aW[6]; acc += h1.w * aW[7];
        acc += h2.x * aW[8]; acc += h2.y * aW[9];
        obase[r * NS] = fmaxf(acc, 0.f);
    }
}

extern "C" void kernel_launch(void* const* d_in, const int* in_sizes, int n_in,
                              void* d_out, int out_size, void* d_ws, size_t ws_size,
                              hipStream_t stream) {
    const float* x     = (const float*)d_in[0];
    const float* times = (const float*)d_in[1];
    const float* mask  = (const float*)d_in[2];
    const float* obsW  = (const float*)d_in[3];
    const float* attnW = (const float*)d_in[4];
    const float* recvW = (const float*)d_in[5];
    const float* recvB = (const float*)d_in[6];
    float* out = (float*)d_out;

    // B*T = 16384 (b,t) pairs, one wave each, 8 waves per block
    raindrop_kernel<<<dim3((NB * NT) / 8), dim3(512), 0, stream>>>(
        x, times, mask, obsW, attnW, recvW, recvB, out);
}